// Round 4
// baseline (746.317 us; speedup 1.0000x reference)
//
#include <hip/hip_runtime.h>
#include <hip/hip_bf16.h>
#include <hip/hip_fp16.h>
#include <math.h>

// T=1024 time steps, S=512 sequences, D=32 features, K=64 states (= wave width)
#define TT 1024
#define SS 512
#define DD 32
#define KK 64

#define LOG2PI_F 1.8378770664093453f

// Workspace: [0,64MB) p''[T,S,K] fp16; then mpart[8192] f32; then seq_logd[512] f32
#define PBUF_BYTES ((size_t)TT * SS * KK * 2)
#define EM_WPB 4
#define EM_BLOCKS 2048
#define NWAVES (EM_BLOCKS * EM_WPB)   // 8192

typedef _Float16 half8 __attribute__((ext_vector_type(8)));
typedef float f32x4 __attribute__((ext_vector_type(4)));

// ---------------------------------------------------------------------------
// Emission: one wave per 64 consecutive (t,s) items; lane = state k.
// v3: wave-uniform x base (readfirstlane -> scalar-load path) + 4-item
// batches so the 6 shuffle-max rounds run as 4 independent latency chains.
__global__ __launch_bounds__(EM_WPB * 64) void emission_kernel(
    const float* __restrict__ data,      // [T,S,D]
    const float* __restrict__ means,     // [K,D]
    const float* __restrict__ covars,    // [K,D]
    __half* __restrict__ pbuf,           // [T,S,K]
    float* __restrict__ mpart)           // [NWAVES]
{
    const int k  = threadIdx.x & 63;
    const int wv = blockIdx.x * EM_WPB + (threadIdx.x >> 6);

    float w[DD], m[DD];
    float c0 = DD * LOG2PI_F;
#pragma unroll
    for (int d = 0; d < DD; ++d) {
        float c = covars[k * DD + d];
        w[d] = 1.0f / c;
        m[d] = means[k * DD + d];
        c0 += __logf(c);
    }

    // wave-uniform item base: lets the compiler treat x addresses as scalar
    const int base = __builtin_amdgcn_readfirstlane(wv) * 64;
    float macc = 0.0f;

    for (int i0 = 0; i0 < 64; i0 += 4) {
        float lp[4];
#pragma unroll
        for (int ii = 0; ii < 4; ++ii) {
            const float4* xp = (const float4*)(data + (size_t)(base + i0 + ii) * DD);
            float q0 = 0.0f, q1 = 0.0f;
#pragma unroll
            for (int d4 = 0; d4 < DD / 4; ++d4) {
                float4 x = xp[d4];
                float t0 = x.x - m[4*d4+0]; q0 = fmaf(w[4*d4+0] * t0, t0, q0);
                float t1 = x.y - m[4*d4+1]; q1 = fmaf(w[4*d4+1] * t1, t1, q1);
                float t2 = x.z - m[4*d4+2]; q0 = fmaf(w[4*d4+2] * t2, t2, q0);
                float t3 = x.w - m[4*d4+3]; q1 = fmaf(w[4*d4+3] * t3, t3, q1);
            }
            lp[ii] = -0.5f * (q0 + q1 + c0);
        }
        float mx[4] = {lp[0], lp[1], lp[2], lp[3]};
#pragma unroll
        for (int off = 32; off > 0; off >>= 1) {
#pragma unroll
            for (int ii = 0; ii < 4; ++ii)
                mx[ii] = fmaxf(mx[ii], __shfl_xor(mx[ii], off, 64));
        }
#pragma unroll
        for (int ii = 0; ii < 4; ++ii) {
            pbuf[(size_t)(base + i0 + ii) * KK + k] =
                __float2half(__expf(lp[ii] - mx[ii]));
            macc += mx[ii];   // wave-uniform
        }
    }
    if (k == 0) mpart[wv] = macc;
}

// ---------------------------------------------------------------------------
// MFMA forward recursion: one wave per 16 sequences (M=16), K=64 states.
// Per step: C = y@trans via 2x mfma_16x16x32_f16 per N-tile (4 tiles);
// z_t = p''_t (.) C * (d_{t-2}/d_{t-1})  [true raw alpha, exactly];
// store y_t = z_t / d_{t-1} as fp16 A-frags (LDS C->A round trip);
// d_t = sum_n z_t (4-round shuffle reduce, OFF the critical path: needed
// only at step t+1). logd accumulates log(d_t) via 4-step products.
__global__ __launch_bounds__(64) void hmm_seq(
    const __half* __restrict__ pbuf,     // [T,S,K]
    const float* __restrict__ initial,   // [K]
    const float* __restrict__ trans,     // [K,K]
    float* __restrict__ out_alpha,       // [S,K]
    float* __restrict__ seq_logd)        // [S]
{
    const int L = threadIdx.x;
    const int sbase = blockIdx.x * 16;

    // C-layout decode (verified m89): C[row=q*4+r][col=tile*16+c], c=L&15, q=L>>4
    const int c = L & 15;
    const int q = L >> 4;
    // A-frag read decode: A[m=L&15][k=f*32+(L>>4)*8+j]
    const int rA  = L & 3;               // r of the C row this lane's m maps to
    const int qCA = (L & 15) >> 2;       // row-block of m
    const int kb  = (L >> 4) & 1;        // within-tile col base /8
    const int th  = (L >> 4) >> 1;       // tile-half selector

    // B fragments of trans (fp16): B[k=(L>>4)*8+j][n=tile*16+c]
    half8 Bf[4][2];
#pragma unroll
    for (int tile = 0; tile < 4; ++tile)
#pragma unroll
        for (int h = 0; h < 2; ++h)
#pragma unroll
            for (int j = 0; j < 8; ++j)
                Bf[tile][h][j] =
                    (_Float16)trans[(h * 32 + q * 8 + j) * KK + tile * 16 + c];

    __shared__ _Float16 LDSH[4 * 4 * 64];   // [tile][r][laneC]

    // p'' gather base: element (sbase+q*4+r)*KK + tile*16 + c at time t.
    // per-lane base covers r via +r*KK, tile via +tile*16 (imm offsets).
    const __half* pb = pbuf + (size_t)(sbase + q * 4) * KK + c;
    const size_t PST = (size_t)SS * KK;

    float d1[4], d2[4], prod[4], logd[4];
    __half pcur[16], pnext[16];

    // ---- boot (t=0): z_0 = initial (.) p''_0, d_{-1}=d_{-2}=1 ----
#pragma unroll
    for (int tile = 0; tile < 4; ++tile)
#pragma unroll
        for (int r = 0; r < 4; ++r)
            pcur[tile * 4 + r] = pb[r * KK + tile * 16];
#pragma unroll
    for (int tile = 0; tile < 4; ++tile)
#pragma unroll
        for (int r = 0; r < 4; ++r)
            pnext[tile * 4 + r] = pb[PST + r * KK + tile * 16];

    float ini[4];
#pragma unroll
    for (int tile = 0; tile < 4; ++tile) ini[tile] = initial[tile * 16 + c];

    float v[4][4];
#pragma unroll
    for (int tile = 0; tile < 4; ++tile)
#pragma unroll
        for (int r = 0; r < 4; ++r)
            v[tile][r] = ini[tile] * __half2float(pcur[tile * 4 + r]);

    // y_0 = z_0 (g=1): convert + LDS round trip
#pragma unroll
    for (int tile = 0; tile < 4; ++tile)
#pragma unroll
        for (int r = 0; r < 4; ++r)
            LDSH[(tile * 4 + r) * 64 + L] = (_Float16)v[tile][r];
    __builtin_amdgcn_wave_barrier();
    half8 aA0 = *(const half8*)&LDSH[(((0 * 2 + th) * 4 + rA) * 64 + qCA * 16 + kb * 8)];
    half8 aA1 = *(const half8*)&LDSH[(((1 * 2 + th) * 4 + rA) * 64 + qCA * 16 + kb * 8)];
    __builtin_amdgcn_wave_barrier();

    float S[4];
#pragma unroll
    for (int r = 0; r < 4; ++r)
        S[r] = ((v[0][r] + v[1][r]) + (v[2][r] + v[3][r]));
#pragma unroll
    for (int msk = 1; msk < 16; msk <<= 1)
#pragma unroll
        for (int r = 0; r < 4; ++r)
            S[r] += __shfl_xor(S[r], msk, 64);
#pragma unroll
    for (int r = 0; r < 4; ++r) {
        d1[r] = S[r];          // d_0
        d2[r] = 1.0f;          // d_{-1}
        prod[r] = S[r];
        logd[r] = 0.0f;
    }

    // ---- main loop t = 1 .. 1022 ----
#pragma unroll 2
    for (int t = 1; t < TT - 1; ++t) {
        // prefetch p'' for t+1
        {
            const __half* ptn = pb + PST * (size_t)(t + 1);
#pragma unroll
            for (int tile = 0; tile < 4; ++tile)
#pragma unroll
                for (int r = 0; r < 4; ++r)
                    pnext[tile * 4 + r] = ptn[r * KK + tile * 16];
        }

        // MFMA: C[tile] = y_{t-1} @ trans (N-tile columns)
        f32x4 C[4];
#pragma unroll
        for (int tile = 0; tile < 4; ++tile) {
            f32x4 z4 = {0.0f, 0.0f, 0.0f, 0.0f};
            z4 = __builtin_amdgcn_mfma_f32_16x16x32_f16(aA0, Bf[tile][0], z4, 0, 0, 0);
            C[tile] = __builtin_amdgcn_mfma_f32_16x16x32_f16(aA1, Bf[tile][1], z4, 0, 0, 0);
        }

        // scalar factors from steps t-1, t-2 (both already known)
        float g[4], corr[4];
#pragma unroll
        for (int r = 0; r < 4; ++r) {
            float rd1 = __builtin_amdgcn_rcpf(d1[r]);
            corr[r] = d2[r] * rd1;          // z_t scale fix
            g[r] = corr[r] * rd1;           // fp16 store scale: d2/d1^2
        }

        // v = C (.) p''  (pre-corr products; reused by S and by the store)
#pragma unroll
        for (int tile = 0; tile < 4; ++tile)
#pragma unroll
            for (int r = 0; r < 4; ++r)
                v[tile][r] = C[tile][r] * __half2float(pcur[tile * 4 + r]);

        // store y_t = v * g to LDS, read back as A-frags
#pragma unroll
        for (int tile = 0; tile < 4; ++tile)
#pragma unroll
            for (int r = 0; r < 4; ++r)
                LDSH[(tile * 4 + r) * 64 + L] = (_Float16)(v[tile][r] * g[r]);
        __builtin_amdgcn_wave_barrier();
        aA0 = *(const half8*)&LDSH[(((0 * 2 + th) * 4 + rA) * 64 + qCA * 16 + kb * 8)];
        aA1 = *(const half8*)&LDSH[(((1 * 2 + th) * 4 + rA) * 64 + qCA * 16 + kb * 8)];
        __builtin_amdgcn_wave_barrier();

        // d_t reduction (overlaps next step's MFMA chain)
#pragma unroll
        for (int r = 0; r < 4; ++r)
            S[r] = ((v[0][r] + v[1][r]) + (v[2][r] + v[3][r]));
#pragma unroll
        for (int msk = 1; msk < 16; msk <<= 1)
#pragma unroll
            for (int r = 0; r < 4; ++r)
                S[r] += __shfl_xor(S[r], msk, 64);
#pragma unroll
        for (int r = 0; r < 4; ++r) {
            float dt = S[r] * corr[r];       // true d_t
            prod[r] *= dt;
            d2[r] = d1[r];
            d1[r] = dt;
        }
        if ((t & 3) == 3) {
#pragma unroll
            for (int r = 0; r < 4; ++r) {
                logd[r] += __logf(prod[r]);
                prod[r] = 1.0f;
            }
        }

        // rotate prefetch
#pragma unroll
        for (int i = 0; i < 16; ++i) pcur[i] = pnext[i];
    }

    // ---- final step t = 1023: compute z, d, write normalized alpha ----
    {
        f32x4 C[4];
#pragma unroll
        for (int tile = 0; tile < 4; ++tile) {
            f32x4 z4 = {0.0f, 0.0f, 0.0f, 0.0f};
            z4 = __builtin_amdgcn_mfma_f32_16x16x32_f16(aA0, Bf[tile][0], z4, 0, 0, 0);
            C[tile] = __builtin_amdgcn_mfma_f32_16x16x32_f16(aA1, Bf[tile][1], z4, 0, 0, 0);
        }
        float corr[4];
#pragma unroll
        for (int r = 0; r < 4; ++r)
            corr[r] = d2[r] * __builtin_amdgcn_rcpf(d1[r]);
#pragma unroll
        for (int tile = 0; tile < 4; ++tile)
#pragma unroll
            for (int r = 0; r < 4; ++r)
                v[tile][r] = C[tile][r] * __half2float(pcur[tile * 4 + r]);
#pragma unroll
        for (int r = 0; r < 4; ++r)
            S[r] = ((v[0][r] + v[1][r]) + (v[2][r] + v[3][r]));
#pragma unroll
        for (int msk = 1; msk < 16; msk <<= 1)
#pragma unroll
            for (int r = 0; r < 4; ++r)
                S[r] += __shfl_xor(S[r], msk, 64);

        float dt[4];
#pragma unroll
        for (int r = 0; r < 4; ++r) {
            dt[r] = S[r] * corr[r];
            prod[r] *= dt[r];
            logd[r] += __logf(prod[r]);      // t=1023 ≡ 3 mod 4: flush
        }
        // alpha = z / d_t = v * corr / dt
#pragma unroll
        for (int tile = 0; tile < 4; ++tile)
#pragma unroll
            for (int r = 0; r < 4; ++r)
                out_alpha[(size_t)(sbase + q * 4 + r) * KK + tile * 16 + c] =
                    v[tile][r] * corr[r] / dt[r];
        if (c == 0) {
#pragma unroll
            for (int r = 0; r < 4; ++r)
                seq_logd[sbase + q * 4 + r] = logd[r];
        }
    }
}

// ---------------------------------------------------------------------------
// nll = -( sum_s seq_logd[s] + sum_w mpart[w] )
__global__ __launch_bounds__(256) void finalize(
    const float* __restrict__ seq_logd, const float* __restrict__ mpart,
    float* __restrict__ out_nll)
{
    float v = 0.0f;
    for (int j = threadIdx.x; j < NWAVES; j += 256) v += mpart[j];
    for (int j = threadIdx.x; j < SS; j += 256) v += seq_logd[j];
#pragma unroll
    for (int off = 32; off > 0; off >>= 1)
        v += __shfl_xor(v, off, 64);
    __shared__ float sh[4];
    if ((threadIdx.x & 63) == 0) sh[threadIdx.x >> 6] = v;
    __syncthreads();
    if (threadIdx.x == 0) {
        double total = ((double)sh[0] + sh[1]) + ((double)sh[2] + sh[3]);
        out_nll[0] = (float)(-total);
    }
}

extern "C" void kernel_launch(void* const* d_in, const int* in_sizes, int n_in,
                              void* d_out, int out_size, void* d_ws, size_t ws_size,
                              hipStream_t stream) {
    const float* data    = (const float*)d_in[0];  // [T,S,D]
    const float* initial = (const float*)d_in[1];  // [K]
    const float* trans   = (const float*)d_in[2];  // [K,K]
    const float* means   = (const float*)d_in[3];  // [K,D]
    const float* covars  = (const float*)d_in[4];  // [K,D]

    float* out_alpha = (float*)d_out;                    // [S,K]
    float* out_nll   = (float*)d_out + (size_t)SS * KK;  // 1 float

    __half* pbuf     = (__half*)d_ws;
    float*  mpart    = (float*)((char*)d_ws + PBUF_BYTES);
    float*  seq_logd = (float*)((char*)d_ws + PBUF_BYTES + NWAVES * sizeof(float));

    emission_kernel<<<EM_BLOCKS, EM_WPB * 64, 0, stream>>>(
        data, means, covars, pbuf, mpart);
    hmm_seq<<<SS / 16, 64, 0, stream>>>(pbuf, initial, trans, out_alpha, seq_logd);
    finalize<<<1, 256, 0, stream>>>(seq_logd, mpart, out_nll);
}